// Round 1
// baseline (2633.066 us; speedup 1.0000x reference)
//
#include <hip/hip_runtime.h>

#define N_NODES 50000
#define N_EDGES 800000
#define D 128
#define ED 64
#define NLAYERS 3

#define NB 24     // dst nodes per block in edge kernel
#define ET 64     // edge tile size
#define APAD 68   // padded leading dim for transposed A tiles (multiple of 4, breaks bank conflicts)

// ---------------- prep kernels (build dst-sorted CSR each call) ----------------

__global__ void hist_kernel(const int* __restrict__ dst, int* __restrict__ deg) {
    int e = blockIdx.x * blockDim.x + threadIdx.x;
    if (e < N_EDGES) atomicAdd(&deg[dst[e]], 1);
}

// single block, 1024 threads. On entry deg_cursor = degrees; on exit
// row_start = exclusive prefix, deg_cursor = copy of row_start (scatter cursor).
__global__ void scan_kernel(int* __restrict__ deg_cursor, int* __restrict__ row_start) {
    __shared__ int part[1024];
    const int t = threadIdx.x;
    const int CH = (N_NODES + 1023) / 1024;  // 49
    int a = t * CH;
    int b = min(a + CH, N_NODES);
    int s = 0;
    for (int i = a; i < b; ++i) s += deg_cursor[i];
    part[t] = s;
    __syncthreads();
    for (int off = 1; off < 1024; off <<= 1) {
        int v = (t >= off) ? part[t - off] : 0;
        __syncthreads();
        part[t] += v;
        __syncthreads();
    }
    int base = (t == 0) ? 0 : part[t - 1];
    for (int i = a; i < b; ++i) {
        int d = deg_cursor[i];
        row_start[i] = base;
        deg_cursor[i] = base;
        base += d;
    }
    if (t == 1023) row_start[N_NODES] = part[1023];
}

__global__ void scatter_kernel(const int* __restrict__ dst, int* __restrict__ cursor,
                               int* __restrict__ perm) {
    int e = blockIdx.x * blockDim.x + threadIdx.x;
    if (e < N_EDGES) {
        int pos = atomicAdd(&cursor[dst[e]], 1);
        perm[pos] = e;
    }
}

// ---------------- fused edge kernel: e = ea@We+be, msg=relu(x[src]+e), LDS-agg by dst, hpre = agg + x ----------------

__global__ __launch_bounds__(256, 2)
void edge_agg_kernel(const float* __restrict__ x,
                     const float* __restrict__ edge_attr,
                     const int* __restrict__ src,
                     const int* __restrict__ perm,
                     const int* __restrict__ dstArr,
                     const int* __restrict__ row_start,
                     const float* __restrict__ We,   // [ED][D]
                     const float* __restrict__ be,   // [D]
                     float* __restrict__ hpre)       // [N][D]
{
    __shared__ float sWe[ED][D];        // 32 KB
    __shared__ float sA[ED][APAD];      // 17 KB : edge_attr tile, transposed [k][edge]
    __shared__ float sAgg[NB][D];       // 12 KB : per-dst accumulators
    __shared__ int   sSrc[ET];
    __shared__ int   sDloc[ET];

    const int t  = threadIdx.x;
    const int n0 = blockIdx.x * NB;
    const int n1 = min(n0 + NB, N_NODES);
    const int nloc = n1 - n0;

    // load We (64*128 floats = 2048 float4)
    {
        const float4* w4 = (const float4*)We;
        float4* s4 = (float4*)&sWe[0][0];
        #pragma unroll
        for (int i = 0; i < 8; ++i) s4[t + i * 256] = w4[t + i * 256];
    }
    // zero sAgg
    {
        float4* s4 = (float4*)&sAgg[0][0];
        for (int i = t; i < NB * D / 4; i += 256) s4[i] = make_float4(0.f, 0.f, 0.f, 0.f);
    }

    const int eStart = row_start[n0];
    const int eEnd   = row_start[n1];

    const int er0 = (t >> 5) * 8;        // 8 edges per thread
    const int c0  = (t & 31) * 4;        // 4 cols per thread
    const float4 bias = *(const float4*)&be[c0];

    for (int tb = eStart; tb < eEnd; tb += ET) {
        const int cnt = min(ET, eEnd - tb);
        __syncthreads();  // previous iter's readers / epilogue done before restage

        // stage edge_attr rows transposed: thread t -> edge i = t&63, quarter part = t>>6
        {
            int i = t & 63;
            int part = t >> 6;
            if (i < cnt) {
                int pe = perm[tb + i];
                if (part == 0) {
                    sSrc[i]  = src[pe];
                    sDloc[i] = dstArr[pe] - n0;
                }
                const float4* row4 = (const float4*)&edge_attr[(size_t)pe * ED];
                #pragma unroll
                for (int q = 0; q < 4; ++q) {
                    float4 v = row4[part * 4 + q];
                    int kb = part * 16 + q * 4;
                    sA[kb + 0][i] = v.x;
                    sA[kb + 1][i] = v.y;
                    sA[kb + 2][i] = v.z;
                    sA[kb + 3][i] = v.w;
                }
            } else if (part == 0) {
                sDloc[i] = -1;
            }
        }
        __syncthreads();

        float acc[8][4];
        #pragma unroll
        for (int e = 0; e < 8; ++e)
            #pragma unroll
            for (int j = 0; j < 4; ++j) acc[e][j] = 0.f;

        for (int k = 0; k < ED; ++k) {
            float4 b4 = *(const float4*)&sWe[k][c0];
            float4 a0 = *(const float4*)&sA[k][er0];
            float4 a1 = *(const float4*)&sA[k][er0 + 4];
            float av[8] = {a0.x, a0.y, a0.z, a0.w, a1.x, a1.y, a1.z, a1.w};
            float bv[4] = {b4.x, b4.y, b4.z, b4.w};
            #pragma unroll
            for (int e = 0; e < 8; ++e)
                #pragma unroll
                for (int j = 0; j < 4; ++j)
                    acc[e][j] = fmaf(av[e], bv[j], acc[e][j]);
        }

        // epilogue: msg = relu(x[src] + e + be), LDS-aggregate per local dst
        #pragma unroll
        for (int e = 0; e < 8; ++e) {
            int ee = er0 + e;
            int dl = sDloc[ee];
            if (dl < 0) continue;
            int sn = sSrc[ee];
            float4 xv = *(const float4*)&x[(size_t)sn * D + c0];
            float m0 = fmaxf(acc[e][0] + bias.x + xv.x, 0.f);
            float m1 = fmaxf(acc[e][1] + bias.y + xv.y, 0.f);
            float m2 = fmaxf(acc[e][2] + bias.z + xv.z, 0.f);
            float m3 = fmaxf(acc[e][3] + bias.w + xv.w, 0.f);
            atomicAdd(&sAgg[dl][c0 + 0], m0);
            atomicAdd(&sAgg[dl][c0 + 1], m1);
            atomicAdd(&sAgg[dl][c0 + 2], m2);
            atomicAdd(&sAgg[dl][c0 + 3], m3);
        }
    }
    __syncthreads();

    // hpre = agg + x
    {
        const float4* x4 = (const float4*)x;
        float4* o4 = (float4*)hpre;
        const float4* s4 = (const float4*)&sAgg[0][0];
        for (int i = t; i < nloc * (D / 4); i += 256) {
            int row = i >> 5;   // D/4 == 32
            int col = i & 31;
            float4 av = s4[row * 32 + col];
            float4 xv = x4[(size_t)(n0 + row) * 32 + col];
            av.x += xv.x; av.y += xv.y; av.z += xv.z; av.w += xv.w;
            o4[(size_t)(n0 + row) * 32 + col] = av;
        }
    }
}

// ---------------- MLP GEMM: out = [relu](in @ W + b) ----------------
// BM=64 rows, BN=128 (all cols), K=128 in two 64-halves (stay under 64KB LDS)

__global__ __launch_bounds__(256, 2)
void mlp_kernel(const float* __restrict__ in,   // [N][D]
                const float* __restrict__ W,    // [D][D]
                const float* __restrict__ bias, // [D]
                float* __restrict__ out,        // [N][D]
                int do_relu)
{
    __shared__ float sWh[64][D];     // 32 KB : W[k0+kl][c]
    __shared__ float sIn[64][APAD];  // 17 KB : input tile transposed [kl][row]

    const int t  = threadIdx.x;
    const int n0 = blockIdx.x * 64;
    const int r0 = (t >> 5) * 8;
    const int c0 = (t & 31) * 4;

    float acc[8][4];
    #pragma unroll
    for (int e = 0; e < 8; ++e)
        #pragma unroll
        for (int j = 0; j < 4; ++j) acc[e][j] = 0.f;

    for (int k0 = 0; k0 < D; k0 += 64) {
        __syncthreads();
        // stage W half
        {
            const float4* w4 = (const float4*)W;
            #pragma unroll
            for (int i = 0; i < 8; ++i) {
                int idx = t + i * 256;
                int kl = idx >> 5, c4 = idx & 31;
                *(float4*)&sWh[kl][c4 * 4] = w4[(size_t)(k0 + kl) * 32 + c4];
            }
        }
        // stage input half, transposed
        {
            int r = t & 63, part = t >> 6;
            int gr = n0 + r;
            #pragma unroll
            for (int q = 0; q < 4; ++q) {
                float4 v = make_float4(0.f, 0.f, 0.f, 0.f);
                if (gr < N_NODES) v = ((const float4*)&in[(size_t)gr * D])[(k0 >> 2) + part * 4 + q];
                int kl = part * 16 + q * 4;
                sIn[kl + 0][r] = v.x;
                sIn[kl + 1][r] = v.y;
                sIn[kl + 2][r] = v.z;
                sIn[kl + 3][r] = v.w;
            }
        }
        __syncthreads();

        for (int kl = 0; kl < 64; ++kl) {
            float4 b4 = *(const float4*)&sWh[kl][c0];
            float4 a0 = *(const float4*)&sIn[kl][r0];
            float4 a1 = *(const float4*)&sIn[kl][r0 + 4];
            float av[8] = {a0.x, a0.y, a0.z, a0.w, a1.x, a1.y, a1.z, a1.w};
            float bv[4] = {b4.x, b4.y, b4.z, b4.w};
            #pragma unroll
            for (int e = 0; e < 8; ++e)
                #pragma unroll
                for (int j = 0; j < 4; ++j)
                    acc[e][j] = fmaf(av[e], bv[j], acc[e][j]);
        }
    }

    float4 bb = *(const float4*)&bias[c0];
    #pragma unroll
    for (int e = 0; e < 8; ++e) {
        int gr = n0 + r0 + e;
        if (gr < N_NODES) {
            float4 o;
            o.x = acc[e][0] + bb.x;
            o.y = acc[e][1] + bb.y;
            o.z = acc[e][2] + bb.z;
            o.w = acc[e][3] + bb.w;
            if (do_relu) {
                o.x = fmaxf(o.x, 0.f); o.y = fmaxf(o.y, 0.f);
                o.z = fmaxf(o.z, 0.f); o.w = fmaxf(o.w, 0.f);
            }
            *(float4*)&out[(size_t)gr * D + c0] = o;
        }
    }
}

// ---------------- host ----------------

extern "C" void kernel_launch(void* const* d_in, const int* in_sizes, int n_in,
                              void* d_out, int out_size, void* d_ws, size_t ws_size,
                              hipStream_t stream) {
    const float* x  = (const float*)d_in[0];
    const int*   ei = (const int*)d_in[1];
    const float* ea = (const float*)d_in[2];
    const float* We = (const float*)d_in[3];
    const float* be = (const float*)d_in[4];
    const float* W1 = (const float*)d_in[5];
    const float* b1 = (const float*)d_in[6];
    const float* W2 = (const float*)d_in[7];
    const float* b2 = (const float*)d_in[8];
    float* out = (float*)d_out;

    const int* src = ei;
    const int* dst = ei + N_EDGES;

    char* ws = (char*)d_ws;
    size_t off = 0;
    auto alloc = [&](size_t bytes) -> char* {
        char* p = ws + off;
        off = (off + bytes + 255) & ~(size_t)255;
        return p;
    };
    float* P         = (float*)alloc((size_t)N_NODES * D * sizeof(float));
    float* T         = (float*)alloc((size_t)N_NODES * D * sizeof(float));
    float* H         = (float*)alloc((size_t)N_NODES * D * sizeof(float));
    int*   perm      = (int*)alloc((size_t)N_EDGES * sizeof(int));
    int*   row_start = (int*)alloc((size_t)(N_NODES + 1) * sizeof(int));
    int*   cursor    = (int*)alloc((size_t)N_NODES * sizeof(int));
    (void)ws_size; (void)in_sizes; (void)n_in; (void)out_size;

    // build dst-sorted CSR (deterministic structure; runs every call)
    hipMemsetAsync(cursor, 0, N_NODES * sizeof(int), stream);
    hist_kernel<<<(N_EDGES + 255) / 256, 256, 0, stream>>>(dst, cursor);
    scan_kernel<<<1, 1024, 0, stream>>>(cursor, row_start);
    scatter_kernel<<<(N_EDGES + 255) / 256, 256, 0, stream>>>(dst, cursor, perm);

    const float* X = x;
    const int egrid = (N_NODES + NB - 1) / NB;
    const int mgrid = (N_NODES + 63) / 64;
    for (int l = 0; l < NLAYERS; ++l) {
        edge_agg_kernel<<<egrid, 256, 0, stream>>>(X, ea, src, perm, dst, row_start,
            We + (size_t)l * ED * D, be + (size_t)l * D, P);
        mlp_kernel<<<mgrid, 256, 0, stream>>>(P, W1 + (size_t)l * D * D, b1 + (size_t)l * D, T, 1);
        float* ob = (l < NLAYERS - 1) ? H : out;
        mlp_kernel<<<mgrid, 256, 0, stream>>>(T, W2 + (size_t)l * D * D, b2 + (size_t)l * D, ob,
                                              (l < NLAYERS - 1) ? 1 : 0);
        X = H;
    }
}

// Round 2
// 2559.185 us; speedup vs baseline: 1.0289x; 1.0289x over previous
//
#include <hip/hip_runtime.h>

#define N_NODES 50000
#define N_EDGES 800000
#define D 128
#define ED 64
#define NLAYERS 3

#define NB 24     // dst nodes per block in edge kernel
#define ET 64     // edge tile size
#define APAD 68   // padded leading dim for transposed A tiles

// ---------------- prep kernels (build dst-sorted CSR each call) ----------------

__global__ void hist_kernel(const int* __restrict__ dst, int* __restrict__ deg) {
    int e = blockIdx.x * blockDim.x + threadIdx.x;
    if (e < N_EDGES) atomicAdd(&deg[dst[e]], 1);
}

// single block, 1024 threads. On entry deg_cursor = degrees; on exit
// row_start = exclusive prefix, deg_cursor = copy of row_start (scatter cursor).
__global__ void scan_kernel(int* __restrict__ deg_cursor, int* __restrict__ row_start) {
    __shared__ int part[1024];
    const int t = threadIdx.x;
    const int CH = (N_NODES + 1023) / 1024;  // 49
    int a = t * CH;
    int b = min(a + CH, N_NODES);
    int s = 0;
    for (int i = a; i < b; ++i) s += deg_cursor[i];
    part[t] = s;
    __syncthreads();
    for (int off = 1; off < 1024; off <<= 1) {
        int v = (t >= off) ? part[t - off] : 0;
        __syncthreads();
        part[t] += v;
        __syncthreads();
    }
    int base = (t == 0) ? 0 : part[t - 1];
    for (int i = a; i < b; ++i) {
        int d = deg_cursor[i];
        row_start[i] = base;
        deg_cursor[i] = base;
        base += d;
    }
    if (t == 1023) row_start[N_NODES] = part[1023];
}

__global__ void scatter_kernel(const int* __restrict__ dst, int* __restrict__ cursor,
                               int* __restrict__ perm) {
    int e = blockIdx.x * blockDim.x + threadIdx.x;
    if (e < N_EDGES) {
        int pos = atomicAdd(&cursor[dst[e]], 1);
        perm[pos] = e;
    }
}

// ---------------- fused edge kernel: e = ea@We+be, msg=relu(x[src]+e), LDS-agg by dst ----------------
// We is NOT staged in LDS: it is 32 KB shared by every block -> L1/L2-resident,
// read as one coalesced 512B wave-load per k-iter. LDS = 30.2 KB -> 5 blocks/CU.

__global__ __launch_bounds__(256, 5)
void edge_agg_kernel(const float* __restrict__ x,
                     const float* __restrict__ edge_attr,
                     const int* __restrict__ src,
                     const int* __restrict__ perm,
                     const int* __restrict__ dstArr,
                     const int* __restrict__ row_start,
                     const float* __restrict__ We,   // [ED][D]
                     const float* __restrict__ be,   // [D]
                     float* __restrict__ hpre)       // [N][D]
{
    __shared__ float sA[ED][APAD];      // 17.4 KB : edge_attr tile, transposed [k][edge]
    __shared__ float sAgg[NB][D];       // 12.3 KB : per-dst accumulators
    __shared__ int   sSrc[ET];
    __shared__ int   sDloc[ET];

    const int t  = threadIdx.x;
    const int n0 = blockIdx.x * NB;
    const int n1 = min(n0 + NB, N_NODES);
    const int nloc = n1 - n0;

    // zero sAgg
    {
        float4* s4 = (float4*)&sAgg[0][0];
        for (int i = t; i < NB * D / 4; i += 256) s4[i] = make_float4(0.f, 0.f, 0.f, 0.f);
    }

    const int eStart = row_start[n0];
    const int eEnd   = row_start[n1];

    const int er0 = (t >> 5) * 8;        // 8 edges per thread
    const int c0  = (t & 31) * 4;        // 4 cols per thread
    const float4 bias = *(const float4*)&be[c0];
    const float* Wc = We + c0;           // column base for B-operand loads

    for (int tb = eStart; tb < eEnd; tb += ET) {
        const int cnt = min(ET, eEnd - tb);
        __syncthreads();  // previous iter's readers / epilogue done before restage

        // stage edge_attr rows transposed: thread t -> edge i = t&63, quarter part = t>>6
        {
            int i = t & 63;
            int part = t >> 6;
            if (i < cnt) {
                int pe = perm[tb + i];
                if (part == 0) {
                    sSrc[i]  = src[pe];
                    sDloc[i] = dstArr[pe] - n0;
                }
                const float4* row4 = (const float4*)&edge_attr[(size_t)pe * ED];
                #pragma unroll
                for (int q = 0; q < 4; ++q) {
                    float4 v = row4[part * 4 + q];
                    int kb = part * 16 + q * 4;
                    sA[kb + 0][i] = v.x;
                    sA[kb + 1][i] = v.y;
                    sA[kb + 2][i] = v.z;
                    sA[kb + 3][i] = v.w;
                }
            } else if (part == 0) {
                sDloc[i] = -1;
            }
        }
        __syncthreads();

        float acc[8][4];
        #pragma unroll
        for (int e = 0; e < 8; ++e)
            #pragma unroll
            for (int j = 0; j < 4; ++j) acc[e][j] = 0.f;

        #pragma unroll 2
        for (int k = 0; k < ED; ++k) {
            float4 b4 = *(const float4*)&Wc[(size_t)k * D];
            float4 a0 = *(const float4*)&sA[k][er0];
            float4 a1 = *(const float4*)&sA[k][er0 + 4];
            float av[8] = {a0.x, a0.y, a0.z, a0.w, a1.x, a1.y, a1.z, a1.w};
            float bv[4] = {b4.x, b4.y, b4.z, b4.w};
            #pragma unroll
            for (int e = 0; e < 8; ++e)
                #pragma unroll
                for (int j = 0; j < 4; ++j)
                    acc[e][j] = fmaf(av[e], bv[j], acc[e][j]);
        }

        // epilogue: msg = relu(x[src] + e + be), LDS-aggregate per local dst
        #pragma unroll
        for (int e = 0; e < 8; ++e) {
            int ee = er0 + e;
            int dl = sDloc[ee];
            if (dl < 0) continue;
            int sn = sSrc[ee];
            float4 xv = *(const float4*)&x[(size_t)sn * D + c0];
            float m0 = fmaxf(acc[e][0] + bias.x + xv.x, 0.f);
            float m1 = fmaxf(acc[e][1] + bias.y + xv.y, 0.f);
            float m2 = fmaxf(acc[e][2] + bias.z + xv.z, 0.f);
            float m3 = fmaxf(acc[e][3] + bias.w + xv.w, 0.f);
            atomicAdd(&sAgg[dl][c0 + 0], m0);
            atomicAdd(&sAgg[dl][c0 + 1], m1);
            atomicAdd(&sAgg[dl][c0 + 2], m2);
            atomicAdd(&sAgg[dl][c0 + 3], m3);
        }
    }
    __syncthreads();

    // hpre = agg + x
    {
        const float4* x4 = (const float4*)x;
        float4* o4 = (float4*)hpre;
        const float4* s4 = (const float4*)&sAgg[0][0];
        for (int i = t; i < nloc * (D / 4); i += 256) {
            int row = i >> 5;   // D/4 == 32
            int col = i & 31;
            float4 av = s4[row * 32 + col];
            float4 xv = x4[(size_t)(n0 + row) * 32 + col];
            av.x += xv.x; av.y += xv.y; av.z += xv.z; av.w += xv.w;
            o4[(size_t)(n0 + row) * 32 + col] = av;
        }
    }
}

// ---------------- MLP GEMM: out = [relu](in @ W + b) ----------------
// BM=32 rows, all 128 cols, full K staged once (one barrier pair, no K-loop
// barriers). W (64 KB) read from global: L2-resident across all blocks.

__global__ __launch_bounds__(256, 6)
void mlp_kernel(const float* __restrict__ in,   // [N][D]
                const float* __restrict__ W,    // [D][D]
                const float* __restrict__ bias, // [D]
                float* __restrict__ out,        // [N][D]
                int do_relu)
{
    __shared__ float sIn[D][36];  // 18.4 KB : input tile transposed [k][row]

    const int t  = threadIdx.x;
    const int n0 = blockIdx.x * 32;
    const int r0 = (t >> 5) * 4;         // 4 rows per thread
    const int c0 = (t & 31) * 4;         // 4 cols per thread

    // stage input tile transposed: thread t -> row r = t&31, part p = t>>5 (8 parts)
    {
        int r = t & 31, p = t >> 5;
        int gr = n0 + r;
        const float4* row4 = (gr < N_NODES) ? (const float4*)&in[(size_t)gr * D] : nullptr;
        #pragma unroll
        for (int q = 0; q < 4; ++q) {
            int f = p * 4 + q;           // float4 index 0..31 -> k = f*4
            float4 v = make_float4(0.f, 0.f, 0.f, 0.f);
            if (row4) v = row4[f];
            int k = f * 4;
            sIn[k + 0][r] = v.x;
            sIn[k + 1][r] = v.y;
            sIn[k + 2][r] = v.z;
            sIn[k + 3][r] = v.w;
        }
    }
    __syncthreads();

    float acc[4][4];
    #pragma unroll
    for (int e = 0; e < 4; ++e)
        #pragma unroll
        for (int j = 0; j < 4; ++j) acc[e][j] = 0.f;

    const float* Wc = W + c0;
    #pragma unroll 4
    for (int k = 0; k < D; ++k) {
        float4 b4 = *(const float4*)&Wc[(size_t)k * D];
        float4 a4 = *(const float4*)&sIn[k][r0];
        float av[4] = {a4.x, a4.y, a4.z, a4.w};
        float bv[4] = {b4.x, b4.y, b4.z, b4.w};
        #pragma unroll
        for (int e = 0; e < 4; ++e)
            #pragma unroll
            for (int j = 0; j < 4; ++j)
                acc[e][j] = fmaf(av[e], bv[j], acc[e][j]);
    }

    float4 bb = *(const float4*)&bias[c0];
    #pragma unroll
    for (int e = 0; e < 4; ++e) {
        int gr = n0 + r0 + e;
        if (gr < N_NODES) {
            float4 o;
            o.x = acc[e][0] + bb.x;
            o.y = acc[e][1] + bb.y;
            o.z = acc[e][2] + bb.z;
            o.w = acc[e][3] + bb.w;
            if (do_relu) {
                o.x = fmaxf(o.x, 0.f); o.y = fmaxf(o.y, 0.f);
                o.z = fmaxf(o.z, 0.f); o.w = fmaxf(o.w, 0.f);
            }
            *(float4*)&out[(size_t)gr * D + c0] = o;
        }
    }
}

// ---------------- host ----------------

extern "C" void kernel_launch(void* const* d_in, const int* in_sizes, int n_in,
                              void* d_out, int out_size, void* d_ws, size_t ws_size,
                              hipStream_t stream) {
    const float* x  = (const float*)d_in[0];
    const int*   ei = (const int*)d_in[1];
    const float* ea = (const float*)d_in[2];
    const float* We = (const float*)d_in[3];
    const float* be = (const float*)d_in[4];
    const float* W1 = (const float*)d_in[5];
    const float* b1 = (const float*)d_in[6];
    const float* W2 = (const float*)d_in[7];
    const float* b2 = (const float*)d_in[8];
    float* out = (float*)d_out;

    const int* src = ei;
    const int* dst = ei + N_EDGES;

    char* ws = (char*)d_ws;
    size_t off = 0;
    auto alloc = [&](size_t bytes) -> char* {
        char* p = ws + off;
        off = (off + bytes + 255) & ~(size_t)255;
        return p;
    };
    float* P         = (float*)alloc((size_t)N_NODES * D * sizeof(float));
    float* T         = (float*)alloc((size_t)N_NODES * D * sizeof(float));
    float* H         = (float*)alloc((size_t)N_NODES * D * sizeof(float));
    int*   perm      = (int*)alloc((size_t)N_EDGES * sizeof(int));
    int*   row_start = (int*)alloc((size_t)(N_NODES + 1) * sizeof(int));
    int*   cursor    = (int*)alloc((size_t)N_NODES * sizeof(int));
    (void)ws_size; (void)in_sizes; (void)n_in; (void)out_size;

    // build dst-sorted CSR (deterministic structure; runs every call)
    hipMemsetAsync(cursor, 0, N_NODES * sizeof(int), stream);
    hist_kernel<<<(N_EDGES + 255) / 256, 256, 0, stream>>>(dst, cursor);
    scan_kernel<<<1, 1024, 0, stream>>>(cursor, row_start);
    scatter_kernel<<<(N_EDGES + 255) / 256, 256, 0, stream>>>(dst, cursor, perm);

    const float* X = x;
    const int egrid = (N_NODES + NB - 1) / NB;
    const int mgrid = (N_NODES + 31) / 32;
    for (int l = 0; l < NLAYERS; ++l) {
        edge_agg_kernel<<<egrid, 256, 0, stream>>>(X, ea, src, perm, dst, row_start,
            We + (size_t)l * ED * D, be + (size_t)l * D, P);
        mlp_kernel<<<mgrid, 256, 0, stream>>>(P, W1 + (size_t)l * D * D, b1 + (size_t)l * D, T, 1);
        float* ob = (l < NLAYERS - 1) ? H : out;
        mlp_kernel<<<mgrid, 256, 0, stream>>>(T, W2 + (size_t)l * D * D, b2 + (size_t)l * D, ob,
                                              (l < NLAYERS - 1) ? 1 : 0);
        X = H;
    }
}

// Round 3
// 2541.272 us; speedup vs baseline: 1.0361x; 1.0070x over previous
//
#include <hip/hip_runtime.h>

#define N_NODES 50000
#define N_EDGES 800000
#define D 128
#define ED 64
#define NLAYERS 3

#define NB 16      // dst nodes per block in edge kernel (50000/16 = 3125 exact)
#define ET 128     // edge tile size
#define APAD 132   // sA row stride (floats)

// ---------------- prep kernels (build dst-sorted CSR each call) ----------------

__global__ void hist_kernel(const int* __restrict__ dst, int* __restrict__ deg) {
    int e = blockIdx.x * blockDim.x + threadIdx.x;
    if (e < N_EDGES) atomicAdd(&deg[dst[e]], 1);
}

__global__ void scan_kernel(int* __restrict__ deg_cursor, int* __restrict__ row_start) {
    __shared__ int part[1024];
    const int t = threadIdx.x;
    const int CH = (N_NODES + 1023) / 1024;  // 49
    int a = t * CH;
    int b = min(a + CH, N_NODES);
    int s = 0;
    for (int i = a; i < b; ++i) s += deg_cursor[i];
    part[t] = s;
    __syncthreads();
    for (int off = 1; off < 1024; off <<= 1) {
        int v = (t >= off) ? part[t - off] : 0;
        __syncthreads();
        part[t] += v;
        __syncthreads();
    }
    int base = (t == 0) ? 0 : part[t - 1];
    for (int i = a; i < b; ++i) {
        int d = deg_cursor[i];
        row_start[i] = base;
        deg_cursor[i] = base;
        base += d;
    }
    if (t == 1023) row_start[N_NODES] = part[1023];
}

__global__ void scatter_kernel(const int* __restrict__ dst, int* __restrict__ cursor,
                               int* __restrict__ perm) {
    int e = blockIdx.x * blockDim.x + threadIdx.x;
    if (e < N_EDGES) {
        int pos = atomicAdd(&cursor[dst[e]], 1);
        perm[pos] = e;
    }
}

// ---------------- fused edge kernel, software-pipelined ----------------
// 512 threads. We in LDS (loop-invariant). Next tile's perm->edge_attr gather
// issued to REGS during current k-loop (T14 issue-early/write-late); x[src]
// gather issued right after stage barrier, consumed after k-loop.

__global__ __launch_bounds__(512, 4)
void edge_agg_kernel(const float* __restrict__ x,
                     const float* __restrict__ edge_attr,
                     const int* __restrict__ src,
                     const int* __restrict__ perm,
                     const int* __restrict__ dstArr,
                     const int* __restrict__ row_start,
                     const float* __restrict__ We,   // [ED][D]
                     const float* __restrict__ be,   // [D]
                     float* __restrict__ hpre)       // [N][D]
{
    __shared__ float sWe[ED][D];        // 32 KB
    __shared__ float sA[ED][APAD];      // 33 KB : edge_attr tile transposed [k][edge]
    __shared__ float sAgg[NB][D];       // 8 KB
    __shared__ int   sSrc[ET];
    __shared__ int   sDloc[ET];

    const int t  = threadIdx.x;
    const int n0 = blockIdx.x * NB;

    const int ei   = t & 127;   // staging edge slot
    const int part = t >> 7;    // 0..3 (each stages 16 consecutive k of its edge)

    // prefetch registers (tile data in flight)
    float4 pa0 = make_float4(0,0,0,0), pa1 = pa0, pa2 = pa0, pa3 = pa0;
    int p_src = 0, p_dloc = -1;

    const int eStart = row_start[n0];
    const int eEnd   = row_start[n0 + NB];

#define ISSUE(tb_, cnt_) do {                                                \
        if (ei < (cnt_)) {                                                   \
            int pe = perm[(tb_) + ei];                                       \
            if (part == 0) { p_src = src[pe]; p_dloc = dstArr[pe] - n0; }    \
            const float4* row4 = (const float4*)&edge_attr[(size_t)pe * ED]; \
            pa0 = row4[part * 4 + 0]; pa1 = row4[part * 4 + 1];              \
            pa2 = row4[part * 4 + 2]; pa3 = row4[part * 4 + 3];              \
        } else if (part == 0) { p_dloc = -1; }                               \
    } while (0)

    // issue first tile's gather immediately; overlaps the We staging below
    ISSUE(eStart, min(ET, eEnd - eStart));

    // stage We (once), zero sAgg, init sSrc
    {
        const float4* w4 = (const float4*)We;
        float4* s4 = (float4*)&sWe[0][0];
        #pragma unroll
        for (int q = 0; q < 4; ++q) s4[t + q * 512] = w4[t + q * 512];
        ((float4*)&sAgg[0][0])[t] = make_float4(0.f, 0.f, 0.f, 0.f);
        if (t < ET) sSrc[t] = 0;
    }

    const int r0 = (t >> 5) * 8;     // 8 edges per thread (half-wave uniform)
    const int c0 = (t & 31) * 4;     // 4 cols per thread
    const float4 bias = *(const float4*)&be[c0];

    for (int tb = eStart; tb < eEnd; tb += ET) {
        __syncthreads();   // prior tile's sA readers done (1st iter: init done)

        // commit in-flight regs -> sA (transposed), write metadata
        {
            const int kb = part * 16;
            sA[kb +  0][ei] = pa0.x; sA[kb +  1][ei] = pa0.y;
            sA[kb +  2][ei] = pa0.z; sA[kb +  3][ei] = pa0.w;
            sA[kb +  4][ei] = pa1.x; sA[kb +  5][ei] = pa1.y;
            sA[kb +  6][ei] = pa1.z; sA[kb +  7][ei] = pa1.w;
            sA[kb +  8][ei] = pa2.x; sA[kb +  9][ei] = pa2.y;
            sA[kb + 10][ei] = pa2.z; sA[kb + 11][ei] = pa2.w;
            sA[kb + 12][ei] = pa3.x; sA[kb + 13][ei] = pa3.y;
            sA[kb + 14][ei] = pa3.z; sA[kb + 15][ei] = pa3.w;
            if (part == 0) { sSrc[ei] = p_src; sDloc[ei] = p_dloc; }
        }
        __syncthreads();   // sA / sSrc / sDloc ready

        // x[src] prefetch for this tile's epilogue (consumed after k-loop)
        float4 xr[8]; int dls[8];
        #pragma unroll
        for (int e = 0; e < 8; ++e) {
            dls[e] = sDloc[r0 + e];
            int sn = sSrc[r0 + e];
            xr[e] = *(const float4*)&x[(size_t)sn * D + c0];
        }

        // issue NEXT tile's gather chain (lands by next commit)
        int ntb = tb + ET;
        if (ntb < eEnd) { ISSUE(ntb, min(ET, eEnd - ntb)); }

        // k-loop: pure LDS
        float acc[8][4];
        #pragma unroll
        for (int e = 0; e < 8; ++e)
            #pragma unroll
            for (int j = 0; j < 4; ++j) acc[e][j] = 0.f;

        #pragma unroll 4
        for (int k = 0; k < ED; ++k) {
            float4 b4 = *(const float4*)&sWe[k][c0];
            float4 a0 = *(const float4*)&sA[k][r0];
            float4 a1 = *(const float4*)&sA[k][r0 + 4];
            float av[8] = {a0.x, a0.y, a0.z, a0.w, a1.x, a1.y, a1.z, a1.w};
            float bv[4] = {b4.x, b4.y, b4.z, b4.w};
            #pragma unroll
            for (int e = 0; e < 8; ++e)
                #pragma unroll
                for (int j = 0; j < 4; ++j)
                    acc[e][j] = fmaf(av[e], bv[j], acc[e][j]);
        }

        // epilogue: msg = relu(x[src] + e + be), aggregate in LDS
        #pragma unroll
        for (int e = 0; e < 8; ++e) {
            if (dls[e] < 0) continue;
            float4 xv = xr[e];
            float m0 = fmaxf(acc[e][0] + bias.x + xv.x, 0.f);
            float m1 = fmaxf(acc[e][1] + bias.y + xv.y, 0.f);
            float m2 = fmaxf(acc[e][2] + bias.z + xv.z, 0.f);
            float m3 = fmaxf(acc[e][3] + bias.w + xv.w, 0.f);
            atomicAdd(&sAgg[dls[e]][c0 + 0], m0);
            atomicAdd(&sAgg[dls[e]][c0 + 1], m1);
            atomicAdd(&sAgg[dls[e]][c0 + 2], m2);
            atomicAdd(&sAgg[dls[e]][c0 + 3], m3);
        }
    }
    __syncthreads();

    // writeout: hpre = agg + x  (16 rows x 32 float4 = 512 = one per thread)
    {
        int row = t >> 5, col = t & 31;
        float4 xv = ((const float4*)&x[(size_t)(n0 + row) * D])[col];
        float4 av = ((const float4*)&sAgg[row][0])[col];
        av.x += xv.x; av.y += xv.y; av.z += xv.z; av.w += xv.w;
        ((float4*)&hpre[(size_t)(n0 + row) * D])[col] = av;
    }
#undef ISSUE
}

// ---------------- MLP GEMM: out = [relu](in @ W + b) ----------------
// BM=64, all 128 cols, K in two 64-halves staged in LDS (pure-LDS k-loop).

__global__ __launch_bounds__(256, 3)
void mlp_kernel(const float* __restrict__ in,   // [N][D]
                const float* __restrict__ W,    // [D][D]
                const float* __restrict__ bias, // [D]
                float* __restrict__ out,        // [N][D]
                int do_relu)
{
    __shared__ float sWh[64][D];     // 32 KB : W[k0+kl][c]
    __shared__ float sIn[64][68];    // 17.4 KB : input tile transposed [kl][row]

    const int t  = threadIdx.x;
    const int n0 = blockIdx.x * 64;
    const int r0 = (t >> 5) * 8;
    const int c0 = (t & 31) * 4;

    float acc[8][4];
    #pragma unroll
    for (int e = 0; e < 8; ++e)
        #pragma unroll
        for (int j = 0; j < 4; ++j) acc[e][j] = 0.f;

    for (int k0 = 0; k0 < D; k0 += 64) {
        __syncthreads();
        // stage W half
        {
            const float4* w4 = (const float4*)W;
            #pragma unroll
            for (int i = 0; i < 8; ++i) {
                int idx = t + i * 256;
                int kl = idx >> 5, c4 = idx & 31;
                *(float4*)&sWh[kl][c4 * 4] = w4[(size_t)(k0 + kl) * 32 + c4];
            }
        }
        // stage input half, transposed
        {
            int r = t & 63, prt = t >> 6;
            int gr = n0 + r;
            #pragma unroll
            for (int q = 0; q < 4; ++q) {
                float4 v = make_float4(0.f, 0.f, 0.f, 0.f);
                if (gr < N_NODES) v = ((const float4*)&in[(size_t)gr * D])[(k0 >> 2) + prt * 4 + q];
                int kl = prt * 16 + q * 4;
                sIn[kl + 0][r] = v.x;
                sIn[kl + 1][r] = v.y;
                sIn[kl + 2][r] = v.z;
                sIn[kl + 3][r] = v.w;
            }
        }
        __syncthreads();

        #pragma unroll 8
        for (int kl = 0; kl < 64; ++kl) {
            float4 b4 = *(const float4*)&sWh[kl][c0];
            float4 a0 = *(const float4*)&sIn[kl][r0];
            float4 a1 = *(const float4*)&sIn[kl][r0 + 4];
            float av[8] = {a0.x, a0.y, a0.z, a0.w, a1.x, a1.y, a1.z, a1.w};
            float bv[4] = {b4.x, b4.y, b4.z, b4.w};
            #pragma unroll
            for (int e = 0; e < 8; ++e)
                #pragma unroll
                for (int j = 0; j < 4; ++j)
                    acc[e][j] = fmaf(av[e], bv[j], acc[e][j]);
        }
    }

    float4 bb = *(const float4*)&bias[c0];
    #pragma unroll
    for (int e = 0; e < 8; ++e) {
        int gr = n0 + r0 + e;
        if (gr < N_NODES) {
            float4 o;
            o.x = acc[e][0] + bb.x;
            o.y = acc[e][1] + bb.y;
            o.z = acc[e][2] + bb.z;
            o.w = acc[e][3] + bb.w;
            if (do_relu) {
                o.x = fmaxf(o.x, 0.f); o.y = fmaxf(o.y, 0.f);
                o.z = fmaxf(o.z, 0.f); o.w = fmaxf(o.w, 0.f);
            }
            *(float4*)&out[(size_t)gr * D + c0] = o;
        }
    }
}

// ---------------- host ----------------

extern "C" void kernel_launch(void* const* d_in, const int* in_sizes, int n_in,
                              void* d_out, int out_size, void* d_ws, size_t ws_size,
                              hipStream_t stream) {
    const float* x  = (const float*)d_in[0];
    const int*   ei = (const int*)d_in[1];
    const float* ea = (const float*)d_in[2];
    const float* We = (const float*)d_in[3];
    const float* be = (const float*)d_in[4];
    const float* W1 = (const float*)d_in[5];
    const float* b1 = (const float*)d_in[6];
    const float* W2 = (const float*)d_in[7];
    const float* b2 = (const float*)d_in[8];
    float* out = (float*)d_out;

    const int* src = ei;
    const int* dst = ei + N_EDGES;

    char* ws = (char*)d_ws;
    size_t off = 0;
    auto alloc = [&](size_t bytes) -> char* {
        char* p = ws + off;
        off = (off + bytes + 255) & ~(size_t)255;
        return p;
    };
    float* P         = (float*)alloc((size_t)N_NODES * D * sizeof(float));
    float* T         = (float*)alloc((size_t)N_NODES * D * sizeof(float));
    float* H         = (float*)alloc((size_t)N_NODES * D * sizeof(float));
    int*   perm      = (int*)alloc((size_t)N_EDGES * sizeof(int));
    int*   row_start = (int*)alloc((size_t)(N_NODES + 1) * sizeof(int));
    int*   cursor    = (int*)alloc((size_t)N_NODES * sizeof(int));
    (void)ws_size; (void)in_sizes; (void)n_in; (void)out_size;

    // build dst-sorted CSR (deterministic structure; runs every call)
    hipMemsetAsync(cursor, 0, N_NODES * sizeof(int), stream);
    hist_kernel<<<(N_EDGES + 255) / 256, 256, 0, stream>>>(dst, cursor);
    scan_kernel<<<1, 1024, 0, stream>>>(cursor, row_start);
    scatter_kernel<<<(N_EDGES + 255) / 256, 256, 0, stream>>>(dst, cursor, perm);

    const float* X = x;
    const int egrid = N_NODES / NB;            // 3125
    const int mgrid = (N_NODES + 63) / 64;     // 782
    for (int l = 0; l < NLAYERS; ++l) {
        edge_agg_kernel<<<egrid, 512, 0, stream>>>(X, ea, src, perm, dst, row_start,
            We + (size_t)l * ED * D, be + (size_t)l * D, P);
        mlp_kernel<<<mgrid, 256, 0, stream>>>(P, W1 + (size_t)l * D * D, b1 + (size_t)l * D, T, 1);
        float* ob = (l < NLAYERS - 1) ? H : out;
        mlp_kernel<<<mgrid, 256, 0, stream>>>(T, W2 + (size_t)l * D * D, b2 + (size_t)l * D, ob,
                                              (l < NLAYERS - 1) ? 1 : 0);
        X = H;
    }
}